// Round 1
// baseline (821.707 us; speedup 1.0000x reference)
//
#include <hip/hip_runtime.h>

typedef unsigned long long ull;

#define W_IMG 1920
#define H_IMG 1080
#define NBOX 4096

// ---- LDS layout for cnn kernel (float offsets) ----
#define S_CROP  0        // [3][24][24]+pad = 1736
#define S_WT1   1736     // [27][32] transposed conv1 weights = 864
#define S_POOL1 8760     // [28][11][12] = 3696
#define S_WT2   0        // [252][24] per-chunk transposed conv2 w = 6048 (reuses dead crop/wt1)
#define S_BUF2  6048     // [24][81] = 1944
#define S_POOL2 7992     // [48][16] = 768
#define S_FEAT  8760     // [576] (reuses dead pool1)
#define S_VEC   9336     // [128]
#define S_LOUT  9464     // [6]
#define SMEM_F  12456    // 49824 B -> 3 blocks/CU

__device__ __forceinline__ float4 ld4(const float* p) { return *(const float4*)p; }
__device__ __forceinline__ float prelu_f(float v, float a) { return v > 0.f ? v : a * v; }

// conv1(3x3, 3->28) + bias + prelu + maxpool(3,2,pad1) fused, one pooled output (4 co) per task
template<int SHIFT, int PMIN>
__device__ __forceinline__ void conv1_pool_task(const float* sm, int cq, int y0, int a0,
                                                float4 bq, float4 aq, float* mx) {
#pragma unroll
  for (int wy = 0; wy < 3; ++wy) {
    int y = y0 + wy;                 // conv output row
    if (y < 0 || y >= 22) continue;  // pool padding row
    float acc0[3] = {0.f,0.f,0.f}, acc1[3] = {0.f,0.f,0.f};
    float acc2[3] = {0.f,0.f,0.f}, acc3[3] = {0.f,0.f,0.f};
#pragma unroll
    for (int c = 0; c < 3; ++c) {
#pragma unroll
      for (int kyy = 0; kyy < 3; ++kyy) {
        float r[8];
        const float* src = sm + S_CROP + c*576 + (y + kyy)*24 + a0;
        *(float4*)&r[0] = ld4(src);
        *(float4*)&r[4] = ld4(src + 4);
#pragma unroll
        for (int kxx = 0; kxx < 3; ++kxx) {
          float4 wq = ld4(sm + S_WT1 + (c*9 + kyy*3 + kxx)*32 + cq*4);
#pragma unroll
          for (int wx = PMIN; wx < 3; ++wx) {
            float v = r[SHIFT + wx + kxx];
            acc0[wx] += v * wq.x; acc1[wx] += v * wq.y;
            acc2[wx] += v * wq.z; acc3[wx] += v * wq.w;
          }
        }
      }
    }
#pragma unroll
    for (int wx = PMIN; wx < 3; ++wx) {
      mx[0] = fmaxf(mx[0], prelu_f(acc0[wx] + bq.x, aq.x));
      mx[1] = fmaxf(mx[1], prelu_f(acc1[wx] + bq.y, aq.y));
      mx[2] = fmaxf(mx[2], prelu_f(acc2[wx] + bq.z, aq.z));
      mx[3] = fmaxf(mx[3], prelu_f(acc3[wx] + bq.w, aq.w));
    }
  }
}

// conv2(3x3, 28->48): 4 channels x P positions per thread, K split over lane pairs
template<int X0, int P>
__device__ __forceinline__ void conv2_compute(float* sm, int cqL, int y, int ks, int ch,
                                              const float* __restrict__ b2,
                                              const float* __restrict__ a2) {
  float acc0[P] = {}, acc1[P] = {}, acc2[P] = {}, acc3[P] = {};
#pragma unroll
  for (int cc = 0; cc < 14; ++cc) {
    int c = ks*14 + cc;
#pragma unroll
    for (int ky = 0; ky < 3; ++ky) {
      float r[8];
      const float* src = sm + S_POOL1 + c*132 + (y + ky)*12 + X0;
      *(float4*)&r[0] = ld4(src);
      *(float4*)&r[4] = ld4(src + 4);
#pragma unroll
      for (int kx = 0; kx < 3; ++kx) {
        float4 wq = ld4(sm + S_WT2 + (c*9 + ky*3 + kx)*24 + cqL*4);
#pragma unroll
        for (int p = 0; p < P; ++p) {
          float v = r[p + kx];
          acc0[p] += v*wq.x; acc1[p] += v*wq.y; acc2[p] += v*wq.z; acc3[p] += v*wq.w;
        }
      }
    }
  }
#pragma unroll
  for (int p = 0; p < P; ++p) {
    acc0[p] += __shfl_xor(acc0[p], 1, 64);
    acc1[p] += __shfl_xor(acc1[p], 1, 64);
    acc2[p] += __shfl_xor(acc2[p], 1, 64);
    acc3[p] += __shfl_xor(acc3[p], 1, 64);
  }
  if (ks == 0) {
    float4 bq = ld4(b2 + ch*24 + cqL*4);
    float4 aq = ld4(a2 + ch*24 + cqL*4);
#pragma unroll
    for (int p = 0; p < P; ++p) {
      sm[S_BUF2 + (cqL*4+0)*81 + y*9 + X0 + p] = prelu_f(acc0[p] + bq.x, aq.x);
      sm[S_BUF2 + (cqL*4+1)*81 + y*9 + X0 + p] = prelu_f(acc1[p] + bq.y, aq.y);
      sm[S_BUF2 + (cqL*4+2)*81 + y*9 + X0 + p] = prelu_f(acc2[p] + bq.z, aq.z);
      sm[S_BUF2 + (cqL*4+3)*81 + y*9 + X0 + p] = prelu_f(acc3[p] + bq.w, aq.w);
    }
  }
}

__global__ __launch_bounds__(256, 3) void cnn_kernel(
    const float* __restrict__ image, const float* __restrict__ bboxes,
    const float* __restrict__ w1, const float* __restrict__ b1, const float* __restrict__ a1,
    const float* __restrict__ w2, const float* __restrict__ b2, const float* __restrict__ a2,
    const float* __restrict__ w3, const float* __restrict__ b3, const float* __restrict__ a3,
    const float* __restrict__ w4, const float* __restrict__ b4, const float* __restrict__ a4,
    const float* __restrict__ w5a, const float* __restrict__ b5a,
    const float* __restrict__ w5b, const float* __restrict__ b5b,
    float* __restrict__ boxes, float* __restrict__ scores)
{
  __shared__ float sm[SMEM_F];
  __shared__ int s_ix[24], s_iy[24];
  const int tid = threadIdx.x;
  const int n = blockIdx.x;

  // ---- Phase A: crop indices + conv1 weight transpose stage ----
  if (tid < 24) {
    int x1 = min(max((int)bboxes[n*4+0], 0), W_IMG);
    int x2 = min(max((int)bboxes[n*4+2], 0), W_IMG);
    s_ix[tid] = min(max(x1 + (tid*(x2-x1))/24, 0), W_IMG-1);
  } else if (tid >= 64 && tid < 88) {
    int j = tid - 64;
    int y1 = min(max((int)bboxes[n*4+1], 0), H_IMG);
    int y2 = min(max((int)bboxes[n*4+3], 0), H_IMG);
    s_iy[j] = min(max(y1 + (j*(y2-y1))/24, 0), H_IMG-1);
  }
  for (int d = tid; d < 756; d += 256) {
    int k = d / 28, co = d % 28;
    sm[S_WT1 + k*32 + co] = w1[co*27 + k];
  }
  __syncthreads();
  // ---- crop + normalize: crop[c][y][x] ----
  for (int e = tid; e < 1728; e += 256) {
    int c = e / 576, rr = e % 576, y = rr / 24, x = rr % 24;
    float v = image[(s_iy[y]*W_IMG + s_ix[x])*3 + c];
    sm[S_CROP + e] = (v - 127.5f) * 0.0078125f;
  }
  __syncthreads();

  // ---- Phase B: conv1+prelu+pool fused -> pool1[28][11][12] ----
  for (int t = tid; t < 7*121; t += 256) {
    int cq = t / 121, rem = t % 121;
    int py = rem / 11, px = rem % 11;
    int y0 = 2*py - 1, x0 = 2*px - 1;
    int a0 = (px == 0) ? 0 : (x0 & ~3);
    float4 bq = ld4(&b1[cq*4]);
    float4 aq = ld4(&a1[cq*4]);
    float mx[4] = {-__builtin_inff(), -__builtin_inff(), -__builtin_inff(), -__builtin_inff()};
    if (px == 0)        conv1_pool_task<-1,1>(sm, cq, y0, a0, bq, aq, mx);
    else if (px & 1)    conv1_pool_task< 1,0>(sm, cq, y0, a0, bq, aq, mx);
    else                conv1_pool_task< 3,0>(sm, cq, y0, a0, bq, aq, mx);
#pragma unroll
    for (int a = 0; a < 4; ++a)
      sm[S_POOL1 + (cq*4+a)*132 + py*12 + px] = mx[a];
  }
  __syncthreads();

  // ---- Phase D: conv2 (2 channel chunks of 24) + pool2 ----
  for (int ch = 0; ch < 2; ++ch) {
    for (int d = tid; d < 6048; d += 256) {          // stage transposed w2 chunk
      int k = d / 24, col = d % 24;
      sm[S_WT2 + d] = w2[(ch*24 + col)*252 + k];
    }
    __syncthreads();
    if (tid < 216) {
      int ks = tid & 1;
      int xh = (tid >> 1) & 1;
      int r2 = tid >> 2;
      int y  = r2 % 9;
      int cqL = r2 / 9;
      if (xh == 0) conv2_compute<0,4>(sm, cqL, y, ks, ch, b2, a2);
      else         conv2_compute<4,5>(sm, cqL, y, ks, ch, b2, a2);
    }
    __syncthreads();
    for (int o = tid; o < 384; o += 256) {           // pool2 (3,2,pad0) for this chunk
      int cl = o / 16, rem = o % 16, pyy = rem / 4, pxx = rem % 4;
      float m = -__builtin_inff();
#pragma unroll
      for (int ky = 0; ky < 3; ++ky)
#pragma unroll
        for (int kx = 0; kx < 3; ++kx)
          m = fmaxf(m, sm[S_BUF2 + cl*81 + (2*pyy+ky)*9 + (2*pxx+kx)]);
      sm[S_POOL2 + (ch*24 + cl)*16 + rem] = m;
    }
    __syncthreads();
  }

  // ---- Phase F: conv3 (2x2, 48->64) -> feat[576] ----
  {
    int co = tid >> 2, ks = tid & 3;
    float acc[9] = {};
    for (int cc = 0; cc < 12; ++cc) {
      int c = ks*12 + cc;
      float r[16];
      *(float4*)&r[0]  = ld4(sm + S_POOL2 + c*16);
      *(float4*)&r[4]  = ld4(sm + S_POOL2 + c*16 + 4);
      *(float4*)&r[8]  = ld4(sm + S_POOL2 + c*16 + 8);
      *(float4*)&r[12] = ld4(sm + S_POOL2 + c*16 + 12);
      float4 wq = ld4(&w3[co*192 + c*4]);
#pragma unroll
      for (int p = 0; p < 9; ++p) {
        int pyy = p / 3, pxx = p % 3;
        acc[p] += r[pyy*4+pxx]*wq.x + r[pyy*4+pxx+1]*wq.y
                + r[(pyy+1)*4+pxx]*wq.z + r[(pyy+1)*4+pxx+1]*wq.w;
      }
    }
#pragma unroll
    for (int p = 0; p < 9; ++p) {
      acc[p] += __shfl_xor(acc[p], 1, 64);
      acc[p] += __shfl_xor(acc[p], 2, 64);
    }
    if (ks == 0) {
      float bb = b3[co], aa = a3[co];
#pragma unroll
      for (int p = 0; p < 9; ++p) sm[S_FEAT + co*9 + p] = prelu_f(acc[p] + bb, aa);
    }
  }
  __syncthreads();

  // ---- Phase G: lin4 (576->128) + prelu ----
  {
    int f = tid >> 1, h = tid & 1;
    const float* wr = w4 + f*576 + h*288;
    const float* fr = sm + S_FEAT + h*288;
    float acc = 0.f;
    for (int j = 0; j < 72; ++j) {
      float4 xv = ld4(fr + j*4);
      float4 wv = ld4(wr + j*4);
      acc += xv.x*wv.x + xv.y*wv.y + xv.z*wv.z + xv.w*wv.w;
    }
    acc += __shfl_xor(acc, 1, 64);
    if (h == 0) sm[S_VEC + f] = prelu_f(acc + b4[f], a4[f]);
  }
  __syncthreads();

  // ---- Phase H: lin5a (softmax) + lin5b (reg) + box regression ----
  if (tid < 6) {
    const float* wr = (tid < 2) ? (w5a + tid*128) : (w5b + (tid-2)*128);
    float acc = 0.f;
#pragma unroll
    for (int j = 0; j < 32; ++j) {
      float4 xv = ld4(sm + S_VEC + j*4);
      float4 wv = ld4(wr + j*4);
      acc += xv.x*wv.x + xv.y*wv.y + xv.z*wv.z + xv.w*wv.w;
    }
    acc += (tid < 2) ? b5a[tid] : b5b[tid-2];
    sm[S_LOUT + tid] = acc;
  }
  __syncthreads();
  if (tid == 0) {
    float l0 = sm[S_LOUT+0], l1 = sm[S_LOUT+1];
    float m = fmaxf(l0, l1);
    float e0 = expf(l0 - m), e1 = expf(l1 - m);
    float sc = e1 / (e0 + e1);
    float4 bb = ld4(&bboxes[n*4]);
    float bw = bb.z - bb.x, bh = bb.w - bb.y;
    float4 ob = make_float4(bb.x + sm[S_LOUT+2]*bw, bb.y + sm[S_LOUT+3]*bh,
                            bb.z + sm[S_LOUT+4]*bw, bb.w + sm[S_LOUT+5]*bh);
    *(float4*)&boxes[n*4] = ob;
    scores[n] = sc;
  }
}

// ---- sort by (-score, idx) via bitonic on packed keys; compact valid count ----
__global__ __launch_bounds__(1024) void sort_kernel(const float* __restrict__ scores,
                                                    const float* __restrict__ boxes,
                                                    int* __restrict__ order,
                                                    float* __restrict__ sboxes,
                                                    int* __restrict__ Vp) {
  __shared__ ull keys[NBOX];
  __shared__ int cnt;
  int tid = threadIdx.x;
  if (tid == 0) cnt = 0;
  __syncthreads();
  int local = 0;
  for (int i = tid; i < NBOX; i += 1024) {
    float s = scores[i];
    bool valid = (s >= 0.7f);
    unsigned hi = valid ? (0xFFFFFFFFu - __float_as_uint(s)) : 0xFFFFFFFFu;
    keys[i] = ((ull)hi << 32) | (unsigned)i;
    if (valid) local++;
  }
  atomicAdd(&cnt, local);
  __syncthreads();
  if (tid == 0) *Vp = cnt;
  for (int k = 2; k <= NBOX; k <<= 1) {
    for (int j = k >> 1; j > 0; j >>= 1) {
      __syncthreads();
      for (int i = tid; i < NBOX; i += 1024) {
        int ij = i ^ j;
        if (ij > i) {
          ull a = keys[i], b = keys[ij];
          bool up = ((i & k) == 0);
          if ((a > b) == up) { keys[i] = b; keys[ij] = a; }
        }
      }
    }
  }
  __syncthreads();
  for (int i = tid; i < NBOX; i += 1024) {
    int idx = (int)(unsigned)(keys[i] & 0xFFFFFFFFu);
    order[i] = idx;
    *(float4*)&sboxes[i*4] = *(const float4*)&boxes[idx*4];
  }
}

// ---- pairwise IoU suppression bitmask: row i, 64 words of bits j ----
__global__ __launch_bounds__(256) void iou_kernel(const float* __restrict__ sboxes,
                                                  const int* __restrict__ Vp,
                                                  ull* __restrict__ mask) {
  int i = blockIdx.x;
  int V = *Vp;
  if (i >= V) return;
  float4 bi = *(const float4*)&sboxes[i*4];
  float ai = fmaxf(bi.z - bi.x, 0.f) * fmaxf(bi.w - bi.y, 0.f);
  int lane = threadIdx.x & 63;
  for (int w = threadIdx.x >> 6; w < 64; w += 4) {
    int j = (w << 6) | lane;
    bool pred = false;
    if (j > i && j < V) {
      float4 bj = *(const float4*)&sboxes[j*4];
      float aj = fmaxf(bj.z - bj.x, 0.f) * fmaxf(bj.w - bj.y, 0.f);
      float xx1 = fmaxf(bi.x, bj.x), yy1 = fmaxf(bi.y, bj.y);
      float xx2 = fminf(bi.z, bj.z), yy2 = fminf(bi.w, bj.w);
      float inter = fmaxf(xx2 - xx1, 0.f) * fmaxf(yy2 - yy1, 0.f);
      float den = fmaxf(ai + aj - inter, 1e-12f);
      pred = (inter / den) > 0.5f;
    }
    ull bits = __ballot(pred);
    if (lane == 0) mask[(size_t)i*64 + w] = bits;
  }
}

// ---- serial greedy NMS scan (single wave, register suppression words) ----
#define CHUNK 16
__global__ __launch_bounds__(64) void nms_scan(const ull* __restrict__ mask,
                                               const int* __restrict__ Vp,
                                               const int* __restrict__ order,
                                               int* __restrict__ keep) {
  int lane = threadIdx.x;
  for (int idx = lane; idx < NBOX; idx += 64) keep[idx] = 0;
  __syncthreads();
  int V = *Vp;
  ull remw = 0;
  __shared__ ull buf[CHUNK][64];
  for (int base = 0; base < V; base += CHUNK) {
    int nn = min(CHUNK, V - base);
#pragma unroll
    for (int r = 0; r < CHUNK; ++r)
      if (r < nn) buf[r][lane] = mask[(size_t)(base + r)*64 + lane];
    for (int r = 0; r < nn; ++r) {
      int i = base + r;
      ull w = __shfl(remw, i >> 6, 64);
      if (!((w >> (i & 63)) & 1ull)) {
        remw |= buf[r][lane];
        if (lane == 0) keep[order[i]] = 1;
      }
    }
  }
}

__global__ __launch_bounds__(256) void out_kernel(const float* __restrict__ boxes,
                                                  const int* __restrict__ keep,
                                                  float* __restrict__ out) {
  int n = blockIdx.x * 256 + threadIdx.x;
  float4 b = *(const float4*)&boxes[n*4];
  float4 z = make_float4(0.f, 0.f, 0.f, 0.f);
  *(float4*)&out[n*4] = keep[n] ? b : z;
}

extern "C" void kernel_launch(void* const* d_in, const int* in_sizes, int n_in,
                              void* d_out, int out_size, void* d_ws, size_t ws_size,
                              hipStream_t stream) {
  const float* image  = (const float*)d_in[0];
  const float* bboxes = (const float*)d_in[1];
  const float* w1  = (const float*)d_in[2];
  const float* b1  = (const float*)d_in[3];
  const float* a1  = (const float*)d_in[4];
  const float* w2  = (const float*)d_in[5];
  const float* b2  = (const float*)d_in[6];
  const float* a2  = (const float*)d_in[7];
  const float* w3  = (const float*)d_in[8];
  const float* b3  = (const float*)d_in[9];
  const float* a3  = (const float*)d_in[10];
  const float* w4  = (const float*)d_in[11];
  const float* b4  = (const float*)d_in[12];
  const float* a4  = (const float*)d_in[13];
  const float* w5a = (const float*)d_in[14];
  const float* b5a = (const float*)d_in[15];
  const float* w5b = (const float*)d_in[16];
  const float* b5b = (const float*)d_in[17];

  // workspace layout (bytes): total 2,277,392 needed
  char* ws = (char*)d_ws;
  float* boxes  = (float*)(ws + 0);        // 4096*4 f32
  float* scores = (float*)(ws + 65536);    // 4096 f32
  float* sboxes = (float*)(ws + 81920);    // 4096*4 f32 (sorted)
  int*   order  = (int*)  (ws + 147456);   // 4096 i32
  int*   Vp     = (int*)  (ws + 163840);   // 1 i32
  int*   keep   = (int*)  (ws + 163856);   // 4096 i32
  ull*   mask   = (ull*)  (ws + 180240);   // 4096*64 u64

  float* out = (float*)d_out;

  cnn_kernel<<<NBOX, 256, 0, stream>>>(image, bboxes, w1,b1,a1, w2,b2,a2, w3,b3,a3,
                                       w4,b4,a4, w5a,b5a, w5b,b5b, boxes, scores);
  sort_kernel<<<1, 1024, 0, stream>>>(scores, boxes, order, sboxes, Vp);
  iou_kernel<<<NBOX, 256, 0, stream>>>(sboxes, Vp, mask);
  nms_scan<<<1, 64, 0, stream>>>(mask, Vp, order, keep);
  out_kernel<<<16, 256, 0, stream>>>(boxes, keep, out);
}

// Round 2
// 772.985 us; speedup vs baseline: 1.0630x; 1.0630x over previous
//
#include <hip/hip_runtime.h>

typedef unsigned long long ull;

#define W_IMG 1920
#define H_IMG 1080
#define NBOX 4096

// ---- LDS layout (float offsets) ----
// Phase A/B (conv1): crop[3][24][28]=2016 | wt1[27][32]=864 | cbuf[28][9][24]=6048 | pool1[28][11][12]=3696
// Phase D (conv2):   wt2[252][24]=6048 | buf2[24][81]=1944 | pool2[48][16]=768 | pool1 (live)
// Phase F/G/H:       feat[576] | vec[128] | lout[6]  (overlap dead wt2 region)
#define S_CROP  0        // stride 28 rows, 672 per channel
#define S_WT1   2016
#define S_CBUF  2880     // [28][9][24], ch stride 216
#define S_POOL1 8928     // [28][11][12], ch stride 132
#define S_WT2   0
#define S_BUF2  6048
#define S_POOL2 7992
#define S_FEAT  0
#define S_VEC   576
#define S_LOUT  704
#define SMEM_F  12624    // 50496 B (+96B idx arrays) -> 3 blocks/CU

__device__ __forceinline__ float4 ld4(const float* p) { return *(const float4*)p; }
__device__ __forceinline__ float prelu_f(float v, float a) { return v > 0.f ? v : a * v; }

// ---- conv1 (3x3, 3->28, VALID 24->22): one strip of WID cols x 4 co, no bias (added after pool) ----
template<int SHIFT, int WID, int NLD>
__device__ __forceinline__ void conv1_task(float* sm, int cq, int y, int cy, int x0, int a0) {
  float acc[4][WID];
#pragma unroll
  for (int a = 0; a < 4; ++a)
#pragma unroll
    for (int wx = 0; wx < WID; ++wx) acc[a][wx] = 0.f;
#pragma unroll
  for (int c = 0; c < 3; ++c) {
#pragma unroll
    for (int kyy = 0; kyy < 3; ++kyy) {
      float r[4*NLD];
      const float* src = sm + S_CROP + c*672 + (cy + kyy)*28 + a0;
#pragma unroll
      for (int q = 0; q < NLD; ++q) *(float4*)&r[4*q] = ld4(src + 4*q);
#pragma unroll
      for (int kxx = 0; kxx < 3; ++kxx) {
        float4 wq = ld4(sm + S_WT1 + (c*9 + kyy*3 + kxx)*32 + cq*4);
#pragma unroll
        for (int wx = 0; wx < WID; ++wx) {
          float v = r[SHIFT + wx + kxx];
          acc[0][wx] += v*wq.x; acc[1][wx] += v*wq.y;
          acc[2][wx] += v*wq.z; acc[3][wx] += v*wq.w;
        }
      }
    }
  }
#pragma unroll
  for (int a = 0; a < 4; ++a)
#pragma unroll
    for (int wx = 0; wx < WID; ++wx)
      sm[S_CBUF + (cq*4 + a)*216 + y*24 + x0 + wx] = acc[a][wx];
}

// conv2(3x3, 28->48): 4 channels x P positions per thread, K split over lane pairs
template<int X0, int P>
__device__ __forceinline__ void conv2_compute(float* sm, int cqL, int y, int ks, int ch,
                                              const float* __restrict__ b2,
                                              const float* __restrict__ a2) {
  float acc0[P] = {}, acc1[P] = {}, acc2[P] = {}, acc3[P] = {};
#pragma unroll
  for (int cc = 0; cc < 14; ++cc) {
    int c = ks*14 + cc;
#pragma unroll
    for (int ky = 0; ky < 3; ++ky) {
      float r[8];
      const float* src = sm + S_POOL1 + c*132 + (y + ky)*12 + X0;
      *(float4*)&r[0] = ld4(src);
      *(float4*)&r[4] = ld4(src + 4);
#pragma unroll
      for (int kx = 0; kx < 3; ++kx) {
        float4 wq = ld4(sm + S_WT2 + (c*9 + ky*3 + kx)*24 + cqL*4);
#pragma unroll
        for (int p = 0; p < P; ++p) {
          float v = r[p + kx];
          acc0[p] += v*wq.x; acc1[p] += v*wq.y; acc2[p] += v*wq.z; acc3[p] += v*wq.w;
        }
      }
    }
  }
#pragma unroll
  for (int p = 0; p < P; ++p) {
    acc0[p] += __shfl_xor(acc0[p], 1, 64);
    acc1[p] += __shfl_xor(acc1[p], 1, 64);
    acc2[p] += __shfl_xor(acc2[p], 1, 64);
    acc3[p] += __shfl_xor(acc3[p], 1, 64);
  }
  if (ks == 0) {
    float4 bq = ld4(b2 + ch*24 + cqL*4);
    float4 aq = ld4(a2 + ch*24 + cqL*4);
#pragma unroll
    for (int p = 0; p < P; ++p) {
      sm[S_BUF2 + (cqL*4+0)*81 + y*9 + X0 + p] = prelu_f(acc0[p] + bq.x, aq.x);
      sm[S_BUF2 + (cqL*4+1)*81 + y*9 + X0 + p] = prelu_f(acc1[p] + bq.y, aq.y);
      sm[S_BUF2 + (cqL*4+2)*81 + y*9 + X0 + p] = prelu_f(acc2[p] + bq.z, aq.z);
      sm[S_BUF2 + (cqL*4+3)*81 + y*9 + X0 + p] = prelu_f(acc3[p] + bq.w, aq.w);
    }
  }
}

__global__ __launch_bounds__(256, 3) void cnn_kernel(
    const float* __restrict__ image, const float* __restrict__ bboxes,
    const float* __restrict__ w1, const float* __restrict__ b1, const float* __restrict__ a1,
    const float* __restrict__ w2, const float* __restrict__ b2, const float* __restrict__ a2,
    const float* __restrict__ w3, const float* __restrict__ b3, const float* __restrict__ a3,
    const float* __restrict__ w4, const float* __restrict__ b4, const float* __restrict__ a4,
    const float* __restrict__ w5a, const float* __restrict__ b5a,
    const float* __restrict__ w5b, const float* __restrict__ b5b,
    float* __restrict__ boxes, float* __restrict__ scores)
{
  __shared__ float sm[SMEM_F];
  __shared__ int s_ix[24], s_iy[24];
  const int tid = threadIdx.x;
  const int n = blockIdx.x;

  // ---- Phase A: crop indices + conv1 weight transpose stage ----
  if (tid < 24) {
    int x1 = min(max((int)bboxes[n*4+0], 0), W_IMG);
    int x2 = min(max((int)bboxes[n*4+2], 0), W_IMG);
    s_ix[tid] = min(max(x1 + (tid*(x2-x1))/24, 0), W_IMG-1);
  } else if (tid >= 64 && tid < 88) {
    int j = tid - 64;
    int y1 = min(max((int)bboxes[n*4+1], 0), H_IMG);
    int y2 = min(max((int)bboxes[n*4+3], 0), H_IMG);
    s_iy[j] = min(max(y1 + (j*(y2-y1))/24, 0), H_IMG-1);
  }
  for (int d = tid; d < 756; d += 256) {
    int k = d / 28, co = d % 28;
    sm[S_WT1 + k*32 + co] = w1[co*27 + k];
  }
  __syncthreads();
  // ---- crop + normalize: crop[c][y][x], row stride 28 ----
  for (int e = tid; e < 1728; e += 256) {
    int c = e / 576, rr = e % 576, y = rr / 24, x = rr % 24;
    float v = image[(s_iy[y]*W_IMG + s_ix[x])*3 + c];
    sm[S_CROP + c*672 + y*28 + x] = (v - 127.5f) * 0.0078125f;
  }
  __syncthreads();

  // ---- Phase B: direct conv1 (no recompute) in 3 y-chunks, then pool (3,2,pad1) ----
  // chunk: conv rows [r0, r0+R), pool rows [p0, p0+np)
  {
    const int c_r0[3] = {0, 7, 15};
    const int c_R [3] = {8, 9, 7};
    const int c_p0[3] = {0, 4, 8};
    const int c_np[3] = {4, 4, 3};
#pragma unroll 1
    for (int ck = 0; ck < 3; ++ck) {
      int r0 = c_r0[ck], R = c_R[ck], p0 = c_p0[ck], np = c_np[ck];
      int nct = 7 * R * 4;
      if (tid < nct) {
        int cq = tid / (R*4), rem = tid % (R*4);
        int y = rem >> 2, xs = rem & 3;
        int cy = r0 + y;
        if (xs == 0)      conv1_task<0,6,2>(sm, cq, y, cy,  0,  0);
        else if (xs == 1) conv1_task<2,6,3>(sm, cq, y, cy,  6,  4);
        else if (xs == 2) conv1_task<0,6,2>(sm, cq, y, cy, 12, 12);
        else              conv1_task<2,4,2>(sm, cq, y, cy, 18, 16);
      }
      __syncthreads();
      int npt = 28 * np * 11;
      for (int t = tid; t < npt; t += 256) {
        int co = t / (np*11), rem = t % (np*11);
        int pyl = rem / 11, px = rem % 11;
        int py = p0 + pyl;
        float m = -__builtin_inff();
        int rlo = max(2*py - 1, 0), rhi = 2*py + 1;           // rhi <= 21 always
        int clo = max(2*px - 1, 0), chi = min(2*px + 1, 21);
        for (int r = rlo; r <= rhi; ++r)
          for (int c = clo; c <= chi; ++c)
            m = fmaxf(m, sm[S_CBUF + co*216 + (r - r0)*24 + c]);
        sm[S_POOL1 + co*132 + py*12 + px] = prelu_f(m + b1[co], a1[co]);
      }
      __syncthreads();
    }
  }

  // ---- Phase D: conv2 (2 channel chunks of 24) + pool2 ----
  for (int ch = 0; ch < 2; ++ch) {
    // stage transposed w2 chunk: coalesced float4 global reads
    for (int d = tid; d < 1512; d += 256) {
      int co = d / 63, kq = d % 63;
      float4 v = ld4(&w2[(ch*24 + co)*252 + 4*kq]);
      int base = S_WT2 + 4*kq*24 + co;
      sm[base     ] = v.x;
      sm[base + 24] = v.y;
      sm[base + 48] = v.z;
      sm[base + 72] = v.w;
    }
    __syncthreads();
    if (tid < 216) {
      int ks = tid & 1;
      int xh = (tid >> 1) & 1;
      int r2 = tid >> 2;
      int y  = r2 % 9;
      int cqL = r2 / 9;
      if (xh == 0) conv2_compute<0,4>(sm, cqL, y, ks, ch, b2, a2);
      else         conv2_compute<4,5>(sm, cqL, y, ks, ch, b2, a2);
    }
    __syncthreads();
    for (int o = tid; o < 384; o += 256) {           // pool2 (3,2,pad0) for this chunk
      int cl = o / 16, rem = o % 16, pyy = rem / 4, pxx = rem % 4;
      float m = -__builtin_inff();
#pragma unroll
      for (int ky = 0; ky < 3; ++ky)
#pragma unroll
        for (int kx = 0; kx < 3; ++kx)
          m = fmaxf(m, sm[S_BUF2 + cl*81 + (2*pyy+ky)*9 + (2*pxx+kx)]);
      sm[S_POOL2 + (ch*24 + cl)*16 + rem] = m;
    }
    __syncthreads();
  }

  // ---- Phase F: conv3 (2x2, 48->64) -> feat[576] ----
  {
    int co = tid >> 2, ks = tid & 3;
    float acc[9] = {};
    for (int cc = 0; cc < 12; ++cc) {
      int c = ks*12 + cc;
      float r[16];
      *(float4*)&r[0]  = ld4(sm + S_POOL2 + c*16);
      *(float4*)&r[4]  = ld4(sm + S_POOL2 + c*16 + 4);
      *(float4*)&r[8]  = ld4(sm + S_POOL2 + c*16 + 8);
      *(float4*)&r[12] = ld4(sm + S_POOL2 + c*16 + 12);
      float4 wq = ld4(&w3[co*192 + c*4]);
#pragma unroll
      for (int p = 0; p < 9; ++p) {
        int pyy = p / 3, pxx = p % 3;
        acc[p] += r[pyy*4+pxx]*wq.x + r[pyy*4+pxx+1]*wq.y
                + r[(pyy+1)*4+pxx]*wq.z + r[(pyy+1)*4+pxx+1]*wq.w;
      }
    }
#pragma unroll
    for (int p = 0; p < 9; ++p) {
      acc[p] += __shfl_xor(acc[p], 1, 64);
      acc[p] += __shfl_xor(acc[p], 2, 64);
    }
    __syncthreads();   // wt2/buf2 region dead; feat region about to be written
    if (ks == 0) {
      float bb = b3[co], aa = a3[co];
#pragma unroll
      for (int p = 0; p < 9; ++p) sm[S_FEAT + co*9 + p] = prelu_f(acc[p] + bb, aa);
    }
  }
  __syncthreads();

  // ---- Phase G: lin4 (576->128) + prelu, coalesced w4 rows + wave reduce ----
  {
    int wv = tid >> 6, lane = tid & 63;
    for (int f = wv; f < 128; f += 4) {
      const float* wr = w4 + f*576;
      float acc = 0.f;
#pragma unroll
      for (int i = 0; i < 9; ++i) {
        int j = i*64 + lane;
        acc += wr[j] * sm[S_FEAT + j];
      }
#pragma unroll
      for (int off = 1; off < 64; off <<= 1) acc += __shfl_xor(acc, off, 64);
      if (lane == 0) sm[S_VEC + f] = prelu_f(acc + b4[f], a4[f]);
    }
  }
  __syncthreads();

  // ---- Phase H: lin5a (softmax) + lin5b (reg) + box regression ----
  if (tid < 6) {
    const float* wr = (tid < 2) ? (w5a + tid*128) : (w5b + (tid-2)*128);
    float acc = 0.f;
#pragma unroll
    for (int j = 0; j < 32; ++j) {
      float4 xv = ld4(sm + S_VEC + j*4);
      float4 wv = ld4(wr + j*4);
      acc += xv.x*wv.x + xv.y*wv.y + xv.z*wv.z + xv.w*wv.w;
    }
    acc += (tid < 2) ? b5a[tid] : b5b[tid-2];
    sm[S_LOUT + tid] = acc;
  }
  __syncthreads();
  if (tid == 0) {
    float l0 = sm[S_LOUT+0], l1 = sm[S_LOUT+1];
    float m = fmaxf(l0, l1);
    float e0 = expf(l0 - m), e1 = expf(l1 - m);
    float sc = e1 / (e0 + e1);
    float4 bb = ld4(&bboxes[n*4]);
    float bw = bb.z - bb.x, bh = bb.w - bb.y;
    float4 ob = make_float4(bb.x + sm[S_LOUT+2]*bw, bb.y + sm[S_LOUT+3]*bh,
                            bb.z + sm[S_LOUT+4]*bw, bb.w + sm[S_LOUT+5]*bh);
    *(float4*)&boxes[n*4] = ob;
    scores[n] = sc;
  }
}

// ---- sort by (-score, idx) via bitonic on packed keys; compact valid count ----
__global__ __launch_bounds__(1024) void sort_kernel(const float* __restrict__ scores,
                                                    const float* __restrict__ boxes,
                                                    int* __restrict__ order,
                                                    float* __restrict__ sboxes,
                                                    int* __restrict__ Vp) {
  __shared__ ull keys[NBOX];
  __shared__ int cnt;
  int tid = threadIdx.x;
  if (tid == 0) cnt = 0;
  __syncthreads();
  int local = 0;
  for (int i = tid; i < NBOX; i += 1024) {
    float s = scores[i];
    bool valid = (s >= 0.7f);
    unsigned hi = valid ? (0xFFFFFFFFu - __float_as_uint(s)) : 0xFFFFFFFFu;
    keys[i] = ((ull)hi << 32) | (unsigned)i;
    if (valid) local++;
  }
  atomicAdd(&cnt, local);
  __syncthreads();
  if (tid == 0) *Vp = cnt;
  for (int k = 2; k <= NBOX; k <<= 1) {
    for (int j = k >> 1; j > 0; j >>= 1) {
      __syncthreads();
      for (int i = tid; i < NBOX; i += 1024) {
        int ij = i ^ j;
        if (ij > i) {
          ull a = keys[i], b = keys[ij];
          bool up = ((i & k) == 0);
          if ((a > b) == up) { keys[i] = b; keys[ij] = a; }
        }
      }
    }
  }
  __syncthreads();
  for (int i = tid; i < NBOX; i += 1024) {
    int idx = (int)(unsigned)(keys[i] & 0xFFFFFFFFu);
    order[i] = idx;
    *(float4*)&sboxes[i*4] = *(const float4*)&boxes[idx*4];
  }
}

// ---- pairwise IoU suppression bitmask: row i, 64 words of bits j ----
__global__ __launch_bounds__(256) void iou_kernel(const float* __restrict__ sboxes,
                                                  const int* __restrict__ Vp,
                                                  ull* __restrict__ mask) {
  int i = blockIdx.x;
  int V = *Vp;
  if (i >= V) return;
  float4 bi = *(const float4*)&sboxes[i*4];
  float ai = fmaxf(bi.z - bi.x, 0.f) * fmaxf(bi.w - bi.y, 0.f);
  int lane = threadIdx.x & 63;
  for (int w = threadIdx.x >> 6; w < 64; w += 4) {
    int j = (w << 6) | lane;
    bool pred = false;
    if (j > i && j < V) {
      float4 bj = *(const float4*)&sboxes[j*4];
      float aj = fmaxf(bj.z - bj.x, 0.f) * fmaxf(bj.w - bj.y, 0.f);
      float xx1 = fmaxf(bi.x, bj.x), yy1 = fmaxf(bi.y, bj.y);
      float xx2 = fminf(bi.z, bj.z), yy2 = fminf(bi.w, bj.w);
      float inter = fmaxf(xx2 - xx1, 0.f) * fmaxf(yy2 - yy1, 0.f);
      float den = fmaxf(ai + aj - inter, 1e-12f);
      pred = (inter / den) > 0.5f;
    }
    ull bits = __ballot(pred);
    if (lane == 0) mask[(size_t)i*64 + w] = bits;
  }
}

// ---- serial greedy NMS scan (single wave, register suppression words) ----
#define CHUNK 16
__global__ __launch_bounds__(64) void nms_scan(const ull* __restrict__ mask,
                                               const int* __restrict__ Vp,
                                               const int* __restrict__ order,
                                               int* __restrict__ keep) {
  int lane = threadIdx.x;
  for (int idx = lane; idx < NBOX; idx += 64) keep[idx] = 0;
  __syncthreads();
  int V = *Vp;
  ull remw = 0;
  __shared__ ull buf[CHUNK][64];
  for (int base = 0; base < V; base += CHUNK) {
    int nn = min(CHUNK, V - base);
#pragma unroll
    for (int r = 0; r < CHUNK; ++r)
      if (r < nn) buf[r][lane] = mask[(size_t)(base + r)*64 + lane];
    for (int r = 0; r < nn; ++r) {
      int i = base + r;
      ull w = __shfl(remw, i >> 6, 64);
      if (!((w >> (i & 63)) & 1ull)) {
        remw |= buf[r][lane];
        if (lane == 0) keep[order[i]] = 1;
      }
    }
  }
}

__global__ __launch_bounds__(256) void out_kernel(const float* __restrict__ boxes,
                                                  const int* __restrict__ keep,
                                                  float* __restrict__ out) {
  int n = blockIdx.x * 256 + threadIdx.x;
  float4 b = *(const float4*)&boxes[n*4];
  float4 z = make_float4(0.f, 0.f, 0.f, 0.f);
  *(float4*)&out[n*4] = keep[n] ? b : z;
}

extern "C" void kernel_launch(void* const* d_in, const int* in_sizes, int n_in,
                              void* d_out, int out_size, void* d_ws, size_t ws_size,
                              hipStream_t stream) {
  const float* image  = (const float*)d_in[0];
  const float* bboxes = (const float*)d_in[1];
  const float* w1  = (const float*)d_in[2];
  const float* b1  = (const float*)d_in[3];
  const float* a1  = (const float*)d_in[4];
  const float* w2  = (const float*)d_in[5];
  const float* b2  = (const float*)d_in[6];
  const float* a2  = (const float*)d_in[7];
  const float* w3  = (const float*)d_in[8];
  const float* b3  = (const float*)d_in[9];
  const float* a3  = (const float*)d_in[10];
  const float* w4  = (const float*)d_in[11];
  const float* b4  = (const float*)d_in[12];
  const float* a4  = (const float*)d_in[13];
  const float* w5a = (const float*)d_in[14];
  const float* b5a = (const float*)d_in[15];
  const float* w5b = (const float*)d_in[16];
  const float* b5b = (const float*)d_in[17];

  char* ws = (char*)d_ws;
  float* boxes  = (float*)(ws + 0);        // 4096*4 f32
  float* scores = (float*)(ws + 65536);    // 4096 f32
  float* sboxes = (float*)(ws + 81920);    // 4096*4 f32 (sorted)
  int*   order  = (int*)  (ws + 147456);   // 4096 i32
  int*   Vp     = (int*)  (ws + 163840);   // 1 i32
  int*   keep   = (int*)  (ws + 163856);   // 4096 i32
  ull*   mask   = (ull*)  (ws + 180240);   // 4096*64 u64

  float* out = (float*)d_out;

  cnn_kernel<<<NBOX, 256, 0, stream>>>(image, bboxes, w1,b1,a1, w2,b2,a2, w3,b3,a3,
                                       w4,b4,a4, w5a,b5a, w5b,b5b, boxes, scores);
  sort_kernel<<<1, 1024, 0, stream>>>(scores, boxes, order, sboxes, Vp);
  iou_kernel<<<NBOX, 256, 0, stream>>>(sboxes, Vp, mask);
  nms_scan<<<1, 64, 0, stream>>>(mask, Vp, order, keep);
  out_kernel<<<16, 256, 0, stream>>>(boxes, keep, out);
}

// Round 3
// 678.988 us; speedup vs baseline: 1.2102x; 1.1384x over previous
//
#include <hip/hip_runtime.h>

typedef unsigned long long ull;

#define W_IMG 1920
#define H_IMG 1080
#define NBOX 4096

// ---- LDS layout (float offsets), total 9432 floats = 37728 B -> 4 blocks/CU ----
// conv1 phase: crop[3][24][28]=2016 | wt1[27][32]=864           | pool1[28][11][12]=3696
// conv2 phase: wt2[126][24]=3024 | buf2[24][81]=1944 | pool2[48][16]=768 | pool1 (live)
// head phase:  feat[576] | vec[128] | lout[6]   (reuse dead front region)
#define S_CROP  0
#define S_WT1   2016
#define S_WT2   0
#define S_BUF2  3024
#define S_POOL2 4968
#define S_POOL1 5736
#define S_FEAT  0
#define S_VEC   576
#define S_LOUT  704
#define SMEM_F  9432

__device__ __forceinline__ float4 ld4(const float* p) { return *(const float4*)p; }
__device__ __forceinline__ float prelu_f(float v, float a) { return v > 0.f ? v : a * v; }

// conv1(3x3,3->28) + maxpool(3,2,pad1) fused: one pooled output x 4 co per task.
// Raw conv max accumulated; bias+prelu applied after (monotone => bitwise-equal).
template<int SHIFT, int PMIN>
__device__ __forceinline__ void conv1_pool_task(const float* sm, int cq, int y0, int a0,
                                                float* mx) {
#pragma unroll
  for (int wy = 0; wy < 3; ++wy) {
    int y = y0 + wy;                 // conv output row, max 21
    if (y < 0) continue;             // pool top padding
    float acc0[3] = {0.f,0.f,0.f}, acc1[3] = {0.f,0.f,0.f};
    float acc2[3] = {0.f,0.f,0.f}, acc3[3] = {0.f,0.f,0.f};
#pragma unroll
    for (int c = 0; c < 3; ++c) {
#pragma unroll
      for (int kyy = 0; kyy < 3; ++kyy) {
        float r[8];
        const float* src = sm + S_CROP + c*672 + (y + kyy)*28 + a0;
        *(float4*)&r[0] = ld4(src);
        *(float4*)&r[4] = ld4(src + 4);
#pragma unroll
        for (int kxx = 0; kxx < 3; ++kxx) {
          float4 wq = ld4(sm + S_WT1 + (c*9 + kyy*3 + kxx)*32 + cq*4);
#pragma unroll
          for (int wx = PMIN; wx < 3; ++wx) {
            float v = r[SHIFT + wx + kxx];
            acc0[wx] += v*wq.x; acc1[wx] += v*wq.y;
            acc2[wx] += v*wq.z; acc3[wx] += v*wq.w;
          }
        }
      }
    }
#pragma unroll
    for (int wx = PMIN; wx < 3; ++wx) {
      mx[0] = fmaxf(mx[0], acc0[wx]);
      mx[1] = fmaxf(mx[1], acc1[wx]);
      mx[2] = fmaxf(mx[2], acc2[wx]);
      mx[3] = fmaxf(mx[3], acc3[wx]);
    }
  }
}

__global__ __launch_bounds__(256, 4) void cnn_kernel(
    const float* __restrict__ image, const float* __restrict__ bboxes,
    const float* __restrict__ w1, const float* __restrict__ b1, const float* __restrict__ a1,
    const float* __restrict__ w2, const float* __restrict__ b2, const float* __restrict__ a2,
    const float* __restrict__ w3, const float* __restrict__ b3, const float* __restrict__ a3,
    const float* __restrict__ w4, const float* __restrict__ b4, const float* __restrict__ a4,
    const float* __restrict__ w5a, const float* __restrict__ b5a,
    const float* __restrict__ w5b, const float* __restrict__ b5b,
    float* __restrict__ boxes, float* __restrict__ scores)
{
  __shared__ float sm[SMEM_F];
  __shared__ int s_ix[24], s_iy[24];
  const int tid = threadIdx.x;
  const int n = blockIdx.x;

  // ---- Phase A: crop indices + conv1 weight transpose stage ----
  if (tid < 24) {
    int x1 = min(max((int)bboxes[n*4+0], 0), W_IMG);
    int x2 = min(max((int)bboxes[n*4+2], 0), W_IMG);
    s_ix[tid] = min(max(x1 + (tid*(x2-x1))/24, 0), W_IMG-1);
  } else if (tid >= 64 && tid < 88) {
    int j = tid - 64;
    int y1 = min(max((int)bboxes[n*4+1], 0), H_IMG);
    int y2 = min(max((int)bboxes[n*4+3], 0), H_IMG);
    s_iy[j] = min(max(y1 + (j*(y2-y1))/24, 0), H_IMG-1);
  }
  for (int d = tid; d < 756; d += 256) {
    int k = d / 28, co = d % 28;
    sm[S_WT1 + k*32 + co] = w1[co*27 + k];
  }
  __syncthreads();
  // ---- crop + normalize: crop[c][y][x], row stride 28 ----
  for (int e = tid; e < 1728; e += 256) {
    int c = e / 576, rr = e % 576, y = rr / 24, x = rr % 24;
    float v = image[(s_iy[y]*W_IMG + s_ix[x])*3 + c];
    sm[S_CROP + c*672 + y*28 + x] = (v - 127.5f) * 0.0078125f;
  }
  __syncthreads();

  // ---- Phase B: conv1+pool fused -> pool1[28][11][12], prelu applied ----
  for (int t = tid; t < 7*121; t += 256) {
    int cq = t / 121, rem = t % 121;
    int py = rem / 11, px = rem % 11;
    int y0 = 2*py - 1, x0 = 2*px - 1;
    int a0 = (px == 0) ? 0 : (x0 & ~3);
    float mx[4] = {-__builtin_inff(), -__builtin_inff(), -__builtin_inff(), -__builtin_inff()};
    if (px == 0)        conv1_pool_task<-1,1>(sm, cq, y0, a0, mx);
    else if (px & 1)    conv1_pool_task< 1,0>(sm, cq, y0, a0, mx);
    else                conv1_pool_task< 3,0>(sm, cq, y0, a0, mx);
    float4 bq = ld4(&b1[cq*4]);
    float4 aq = ld4(&a1[cq*4]);
    sm[S_POOL1 + (cq*4+0)*132 + py*12 + px] = prelu_f(mx[0] + bq.x, aq.x);
    sm[S_POOL1 + (cq*4+1)*132 + py*12 + px] = prelu_f(mx[1] + bq.y, aq.y);
    sm[S_POOL1 + (cq*4+2)*132 + py*12 + px] = prelu_f(mx[2] + bq.z, aq.z);
    sm[S_POOL1 + (cq*4+3)*132 + py*12 + px] = prelu_f(mx[3] + bq.w, aq.w);
  }
  __syncthreads();

  // ---- Phase D: conv2 (2 co-chunks x 2 K-half stages), fat threads:
  //      thread = (cqL 0..5, y 0..8, ks 0..1), 4 co x 9 positions in regs ----
  for (int ch = 0; ch < 2; ++ch) {
    float acc0[9] = {}, acc1[9] = {}, acc2[9] = {}, acc3[9] = {};
    const int ks = tid & 1, r2 = tid >> 1;
    const int y = r2 % 9, cqL = r2 / 9;
#pragma unroll 1
    for (int h = 0; h < 2; ++h) {
      // stage wt2 K-half h (channels h*14..h*14+13), transposed [126 k][24 co]
      for (int d = tid; d < 1512; d += 256) {
        int co = d / 63, j = d % 63;
        float2 v = *(const float2*)&w2[(ch*24 + co)*252 + h*126 + 2*j];
        sm[S_WT2 + (2*j  )*24 + co] = v.x;
        sm[S_WT2 + (2*j+1)*24 + co] = v.y;
      }
      __syncthreads();
      if (tid < 108) {
#pragma unroll 1
        for (int cc = 0; cc < 7; ++cc) {
          int cl = ks*7 + cc;          // k-index within staged half
          int c  = h*14 + cl;          // global input channel
#pragma unroll
          for (int ky = 0; ky < 3; ++ky) {
            float rw[12];
            const float* src = sm + S_POOL1 + c*132 + (y + ky)*12;
            *(float4*)&rw[0] = ld4(src);
            *(float4*)&rw[4] = ld4(src + 4);
            *(float4*)&rw[8] = ld4(src + 8);
#pragma unroll
            for (int kx = 0; kx < 3; ++kx) {
              float4 wq = ld4(sm + S_WT2 + ((cl*3 + ky)*3 + kx)*24 + cqL*4);
#pragma unroll
              for (int p = 0; p < 9; ++p) {
                float v = rw[p + kx];
                acc0[p] += v*wq.x; acc1[p] += v*wq.y;
                acc2[p] += v*wq.z; acc3[p] += v*wq.w;
              }
            }
          }
        }
      }
      __syncthreads();   // staged weights free for restage / buf2 write next
    }
    if (tid < 108) {
#pragma unroll
      for (int p = 0; p < 9; ++p) {
        acc0[p] += __shfl_xor(acc0[p], 1, 64);
        acc1[p] += __shfl_xor(acc1[p], 1, 64);
        acc2[p] += __shfl_xor(acc2[p], 1, 64);
        acc3[p] += __shfl_xor(acc3[p], 1, 64);
      }
      if (ks == 0) {
        float4 bq = ld4(b2 + ch*24 + cqL*4);
        float4 aq = ld4(a2 + ch*24 + cqL*4);
#pragma unroll
        for (int p = 0; p < 9; ++p) {
          sm[S_BUF2 + (cqL*4+0)*81 + y*9 + p] = prelu_f(acc0[p] + bq.x, aq.x);
          sm[S_BUF2 + (cqL*4+1)*81 + y*9 + p] = prelu_f(acc1[p] + bq.y, aq.y);
          sm[S_BUF2 + (cqL*4+2)*81 + y*9 + p] = prelu_f(acc2[p] + bq.z, aq.z);
          sm[S_BUF2 + (cqL*4+3)*81 + y*9 + p] = prelu_f(acc3[p] + bq.w, aq.w);
        }
      }
    }
    __syncthreads();
    for (int o = tid; o < 384; o += 256) {           // pool2 (3,2,pad0) for this chunk
      int cl = o / 16, rem = o % 16, pyy = rem / 4, pxx = rem % 4;
      float m = -__builtin_inff();
#pragma unroll
      for (int ky = 0; ky < 3; ++ky)
#pragma unroll
        for (int kx = 0; kx < 3; ++kx)
          m = fmaxf(m, sm[S_BUF2 + cl*81 + (2*pyy+ky)*9 + (2*pxx+kx)]);
      sm[S_POOL2 + (ch*24 + cl)*16 + rem] = m;
    }
    __syncthreads();
  }

  // ---- Phase F: conv3 (2x2, 48->64) -> feat[576] ----
  {
    int co = tid >> 2, ks = tid & 3;
    float acc[9] = {};
    for (int cc = 0; cc < 12; ++cc) {
      int c = ks*12 + cc;
      float r[16];
      *(float4*)&r[0]  = ld4(sm + S_POOL2 + c*16);
      *(float4*)&r[4]  = ld4(sm + S_POOL2 + c*16 + 4);
      *(float4*)&r[8]  = ld4(sm + S_POOL2 + c*16 + 8);
      *(float4*)&r[12] = ld4(sm + S_POOL2 + c*16 + 12);
      float4 wq = ld4(&w3[co*192 + c*4]);
#pragma unroll
      for (int p = 0; p < 9; ++p) {
        int pyy = p / 3, pxx = p % 3;
        acc[p] += r[pyy*4+pxx]*wq.x + r[pyy*4+pxx+1]*wq.y
                + r[(pyy+1)*4+pxx]*wq.z + r[(pyy+1)*4+pxx+1]*wq.w;
      }
    }
#pragma unroll
    for (int p = 0; p < 9; ++p) {
      acc[p] += __shfl_xor(acc[p], 1, 64);
      acc[p] += __shfl_xor(acc[p], 2, 64);
    }
    if (ks == 0) {
      float bb = b3[co], aa = a3[co];
#pragma unroll
      for (int p = 0; p < 9; ++p) sm[S_FEAT + co*9 + p] = prelu_f(acc[p] + bb, aa);
    }
  }
  __syncthreads();

  // ---- Phase G: lin4 (576->128) + prelu, coalesced w4 rows + wave reduce ----
  {
    int wv = tid >> 6, lane = tid & 63;
    for (int f = wv; f < 128; f += 4) {
      const float* wr = w4 + f*576;
      float acc = 0.f;
#pragma unroll
      for (int i = 0; i < 9; ++i) {
        int j = i*64 + lane;
        acc += wr[j] * sm[S_FEAT + j];
      }
#pragma unroll
      for (int off = 1; off < 64; off <<= 1) acc += __shfl_xor(acc, off, 64);
      if (lane == 0) sm[S_VEC + f] = prelu_f(acc + b4[f], a4[f]);
    }
  }
  __syncthreads();

  // ---- Phase H: lin5a (softmax) + lin5b (reg) + box regression ----
  if (tid < 6) {
    const float* wr = (tid < 2) ? (w5a + tid*128) : (w5b + (tid-2)*128);
    float acc = 0.f;
#pragma unroll
    for (int j = 0; j < 32; ++j) {
      float4 xv = ld4(sm + S_VEC + j*4);
      float4 wv = ld4(wr + j*4);
      acc += xv.x*wv.x + xv.y*wv.y + xv.z*wv.z + xv.w*wv.w;
    }
    acc += (tid < 2) ? b5a[tid] : b5b[tid-2];
    sm[S_LOUT + tid] = acc;
  }
  __syncthreads();
  if (tid == 0) {
    float l0 = sm[S_LOUT+0], l1 = sm[S_LOUT+1];
    float m = fmaxf(l0, l1);
    float e0 = expf(l0 - m), e1 = expf(l1 - m);
    float sc = e1 / (e0 + e1);
    float4 bb = ld4(&bboxes[n*4]);
    float bw = bb.z - bb.x, bh = bb.w - bb.y;
    float4 ob = make_float4(bb.x + sm[S_LOUT+2]*bw, bb.y + sm[S_LOUT+3]*bh,
                            bb.z + sm[S_LOUT+4]*bw, bb.w + sm[S_LOUT+5]*bh);
    *(float4*)&boxes[n*4] = ob;
    scores[n] = sc;
  }
}

// ---- sort by (-score, idx) via bitonic on packed keys; compact valid count ----
__global__ __launch_bounds__(1024) void sort_kernel(const float* __restrict__ scores,
                                                    const float* __restrict__ boxes,
                                                    int* __restrict__ order,
                                                    float* __restrict__ sboxes,
                                                    int* __restrict__ Vp) {
  __shared__ ull keys[NBOX];
  __shared__ int cnt;
  int tid = threadIdx.x;
  if (tid == 0) cnt = 0;
  __syncthreads();
  int local = 0;
  for (int i = tid; i < NBOX; i += 1024) {
    float s = scores[i];
    bool valid = (s >= 0.7f);
    unsigned hi = valid ? (0xFFFFFFFFu - __float_as_uint(s)) : 0xFFFFFFFFu;
    keys[i] = ((ull)hi << 32) | (unsigned)i;
    if (valid) local++;
  }
  atomicAdd(&cnt, local);
  __syncthreads();
  if (tid == 0) *Vp = cnt;
  for (int k = 2; k <= NBOX; k <<= 1) {
    for (int j = k >> 1; j > 0; j >>= 1) {
      __syncthreads();
      for (int i = tid; i < NBOX; i += 1024) {
        int ij = i ^ j;
        if (ij > i) {
          ull a = keys[i], b = keys[ij];
          bool up = ((i & k) == 0);
          if ((a > b) == up) { keys[i] = b; keys[ij] = a; }
        }
      }
    }
  }
  __syncthreads();
  for (int i = tid; i < NBOX; i += 1024) {
    int idx = (int)(unsigned)(keys[i] & 0xFFFFFFFFu);
    order[i] = idx;
    *(float4*)&sboxes[i*4] = *(const float4*)&boxes[idx*4];
  }
}

// ---- pairwise IoU suppression bitmask: row i, 64 words of bits j ----
__global__ __launch_bounds__(256) void iou_kernel(const float* __restrict__ sboxes,
                                                  const int* __restrict__ Vp,
                                                  ull* __restrict__ mask) {
  int i = blockIdx.x;
  int V = *Vp;
  if (i >= V) return;
  float4 bi = *(const float4*)&sboxes[i*4];
  float ai = fmaxf(bi.z - bi.x, 0.f) * fmaxf(bi.w - bi.y, 0.f);
  int lane = threadIdx.x & 63;
  for (int w = threadIdx.x >> 6; w < 64; w += 4) {
    int j = (w << 6) | lane;
    bool pred = false;
    if (j > i && j < V) {
      float4 bj = *(const float4*)&sboxes[j*4];
      float aj = fmaxf(bj.z - bj.x, 0.f) * fmaxf(bj.w - bj.y, 0.f);
      float xx1 = fmaxf(bi.x, bj.x), yy1 = fmaxf(bi.y, bj.y);
      float xx2 = fminf(bi.z, bj.z), yy2 = fminf(bi.w, bj.w);
      float inter = fmaxf(xx2 - xx1, 0.f) * fmaxf(yy2 - yy1, 0.f);
      float den = fmaxf(ai + aj - inter, 1e-12f);
      pred = (inter / den) > 0.5f;
    }
    ull bits = __ballot(pred);
    if (lane == 0) mask[(size_t)i*64 + w] = bits;
  }
}

// ---- serial greedy NMS scan (single wave, register suppression words) ----
#define CHUNK 16
__global__ __launch_bounds__(64) void nms_scan(const ull* __restrict__ mask,
                                               const int* __restrict__ Vp,
                                               const int* __restrict__ order,
                                               int* __restrict__ keep) {
  int lane = threadIdx.x;
  for (int idx = lane; idx < NBOX; idx += 64) keep[idx] = 0;
  __syncthreads();
  int V = *Vp;
  ull remw = 0;
  __shared__ ull buf[CHUNK][64];
  for (int base = 0; base < V; base += CHUNK) {
    int nn = min(CHUNK, V - base);
#pragma unroll
    for (int r = 0; r < CHUNK; ++r)
      if (r < nn) buf[r][lane] = mask[(size_t)(base + r)*64 + lane];
    for (int r = 0; r < nn; ++r) {
      int i = base + r;
      ull w = __shfl(remw, i >> 6, 64);
      if (!((w >> (i & 63)) & 1ull)) {
        remw |= buf[r][lane];
        if (lane == 0) keep[order[i]] = 1;
      }
    }
  }
}

__global__ __launch_bounds__(256) void out_kernel(const float* __restrict__ boxes,
                                                  const int* __restrict__ keep,
                                                  float* __restrict__ out) {
  int n = blockIdx.x * 256 + threadIdx.x;
  float4 b = *(const float4*)&boxes[n*4];
  float4 z = make_float4(0.f, 0.f, 0.f, 0.f);
  *(float4*)&out[n*4] = keep[n] ? b : z;
}

extern "C" void kernel_launch(void* const* d_in, const int* in_sizes, int n_in,
                              void* d_out, int out_size, void* d_ws, size_t ws_size,
                              hipStream_t stream) {
  const float* image  = (const float*)d_in[0];
  const float* bboxes = (const float*)d_in[1];
  const float* w1  = (const float*)d_in[2];
  const float* b1  = (const float*)d_in[3];
  const float* a1  = (const float*)d_in[4];
  const float* w2  = (const float*)d_in[5];
  const float* b2  = (const float*)d_in[6];
  const float* a2  = (const float*)d_in[7];
  const float* w3  = (const float*)d_in[8];
  const float* b3  = (const float*)d_in[9];
  const float* a3  = (const float*)d_in[10];
  const float* w4  = (const float*)d_in[11];
  const float* b4  = (const float*)d_in[12];
  const float* a4  = (const float*)d_in[13];
  const float* w5a = (const float*)d_in[14];
  const float* b5a = (const float*)d_in[15];
  const float* w5b = (const float*)d_in[16];
  const float* b5b = (const float*)d_in[17];

  char* ws = (char*)d_ws;
  float* boxes  = (float*)(ws + 0);        // 4096*4 f32
  float* scores = (float*)(ws + 65536);    // 4096 f32
  float* sboxes = (float*)(ws + 81920);    // 4096*4 f32 (sorted)
  int*   order  = (int*)  (ws + 147456);   // 4096 i32
  int*   Vp     = (int*)  (ws + 163840);   // 1 i32
  int*   keep   = (int*)  (ws + 163856);   // 4096 i32
  ull*   mask   = (ull*)  (ws + 180240);   // 4096*64 u64

  float* out = (float*)d_out;

  cnn_kernel<<<NBOX, 256, 0, stream>>>(image, bboxes, w1,b1,a1, w2,b2,a2, w3,b3,a3,
                                       w4,b4,a4, w5a,b5a, w5b,b5b, boxes, scores);
  sort_kernel<<<1, 1024, 0, stream>>>(scores, boxes, order, sboxes, Vp);
  iou_kernel<<<NBOX, 256, 0, stream>>>(sboxes, Vp, mask);
  nms_scan<<<1, 64, 0, stream>>>(mask, Vp, order, keep);
  out_kernel<<<16, 256, 0, stream>>>(boxes, keep, out);
}